// Round 6
// baseline (2272.571 us; speedup 1.0000x reference)
//
#include <hip/hip_runtime.h>
#include <cstdint>

typedef __attribute__((ext_vector_type(4))) _Float16 f16x4;
typedef __attribute__((ext_vector_type(8))) _Float16 f16x8;
typedef __attribute__((ext_vector_type(4))) float f32x4;

#define D_DIM 1024
#define H_DIM 4096
#define BS_ROWS 8192
#define K_SEL 524288u
#define CAND_CAP 32768u

// order-isomorphic fp32 -> uint linear key (monotone; collisions ~2^-22 window, safe)
__device__ __forceinline__ unsigned lkey(float v){
  float u = fmaf(v, 67108864.f, 268435456.f);          // (v+4)*2^26, single rounding
  u = fminf(fmaxf(u, 0.f), 536870911.f);               // clamp to [0, 2^29)
  return (unsigned)u;
}

// async global->LDS, 16B per lane (dest = wave-uniform base + lane*16)
__device__ __forceinline__ void gload16(const _Float16* g, _Float16* l){
  __builtin_amdgcn_global_load_lds(
      (const __attribute__((address_space(1))) void*)g,
      (__attribute__((address_space(3))) void*)l, 16, 0, 0);
}

template<int N> __device__ __forceinline__ void waitcnt_vm(){
  if      constexpr (N == 0) asm volatile("s_waitcnt vmcnt(0)" ::: "memory");
  else if constexpr (N == 4) asm volatile("s_waitcnt vmcnt(4)" ::: "memory");
  else if constexpr (N == 6) asm volatile("s_waitcnt vmcnt(6)" ::: "memory");
  else                       asm volatile("s_waitcnt vmcnt(8)" ::: "memory");
}

// Tiled fp16 image: tiles of 128 rows x 32 halves (8KB, 512 granules of 16B).
// Granule for (row,k8): p=(row&127)>>1, s=((row&1)<<2|(k8&3))^(p&7); index p*8+s.
__device__ __forceinline__ size_t img_g32(int row, int k8, int nkt32){
  int p = (row & 127) >> 1;
  int s = (((row & 1) << 2) | (k8 & 3)) ^ (p & 7);
  return ((size_t)((row >> 7) * nkt32 + (k8 >> 2)) << 9) + (p << 3) + s;
}

template<bool LO>
__global__ __launch_bounds__(256)
void pack_img(const float* __restrict__ W, _Float16* __restrict__ hi,
              _Float16* __restrict__ lo, int k8shift, int nkt32, int total)
{
  int g = blockIdx.x * 256 + threadIdx.x;
  if (g >= total) return;
  int row = g >> k8shift, k8 = g & ((1 << k8shift) - 1);
  const float* src = W + ((size_t)row << (k8shift + 3)) + (k8 << 3);
  float4 f0 = *(const float4*)src, f1 = *(const float4*)(src + 4);
  float ff[8] = {f0.x,f0.y,f0.z,f0.w,f1.x,f1.y,f1.z,f1.w};
  f16x8 hv, lv;
  #pragma unroll
  for (int i = 0; i < 8; i++){
    hv[i] = (_Float16)ff[i];
    if (LO) lv[i] = (_Float16)(ff[i] - (float)hv[i]);
  }
  size_t d = img_g32(row, k8, nkt32) << 3;
  *(f16x8*)&hi[d] = hv;
  if (LO) *(f16x8*)&lo[d] = lv;
}

enum { MODE_G1 = 0, MODE_G2 = 1, MODE_UPMOD = 2, MODE_DOWN = 3 };

// C = A[M,K] * B[N,K]^T + bias.  A/B are tiled fp16 images.
// NSEG==3 (G1,G2): acc = Ahi*Bhi + Alo*Bhi + Ahi*Blo  (~fp32 accuracy).
// Double-buffered LDS, counted vmcnt, raw s_barrier (T3/T4 minimum pipeline).
template<int MODE>
__global__ __launch_bounds__(256)
void gemm_t(const _Float16* __restrict__ Ahi, const _Float16* __restrict__ Alo,
            const _Float16* __restrict__ Bhi, const _Float16* __restrict__ Blo,
            const float* __restrict__ bias0, const float* __restrict__ bias1,
            const unsigned* __restrict__ mask,
            _Float16* __restrict__ Chi, _Float16* __restrict__ Clo,
            float* __restrict__ C32,
            unsigned* __restrict__ keys, unsigned* __restrict__ Mkey,
            unsigned* __restrict__ hist,
            int N, int K, int m_img_base, int c_row_base, int batch_base)
{
  constexpr int NSEG = (MODE == MODE_G1 || MODE == MODE_G2) ? 3 : 1;
  constexpr bool BSEL = (MODE == MODE_UPMOD);
  constexpr int NLD = (NSEG == 3) ? 8 : (BSEL ? 6 : 4);
  __shared__ __align__(16) _Float16 sA [2][4096];
  __shared__ __align__(16) _Float16 sB [2][4096];
  __shared__ __align__(16) _Float16 sAl[NSEG == 3 ? 2 : 1][NSEG == 3 ? 4096 : 8];
  __shared__ __align__(16) _Float16 sBl[(NSEG == 3 || BSEL) ? 2 : 1][(NSEG == 3 || BSEL) ? 4096 : 8];
  __shared__ unsigned lh[MODE == MODE_G2 ? 4096 : 1];

  // XCD-aware block swizzle (all grids have nwg % 8 == 0)
  const int nbx = gridDim.x;
  int wg = blockIdx.y * nbx + blockIdx.x;
  const int nwg = nbx * gridDim.y;
  wg = (wg & 7) * (nwg >> 3) + (wg >> 3);
  const int bx = wg % nbx, by = wg / nbx;

  const int tid = threadIdx.x;
  const int lane = tid & 63;
  const int w  = tid >> 6;
  const int wr = w >> 1, wc = w & 1;
  const int lr = lane & 15;
  const int q  = lane >> 4;

  const int m0 = m_img_base + by * 128;
  const int n0 = bx * 128;
  const int nkt = K >> 5;
  const size_t arow = (size_t)(m0 >> 7) * nkt;
  const size_t brow = (size_t)(n0 >> 7) * nkt;

  // UPMOD: per-fragment-row B select (up vs mod), resolved before the loop
  const _Float16* bbase[4];
  if (BSEL){
    const int bb = m0 >> 9;
    #pragma unroll
    for (int i = 0; i < 4; i++){
      int row = wc*64 + i*16 + lr;
      bbase[i] = mask[bb * H_DIM + n0 + row] ? &sBl[0][0] : &sB[0][0];
    }
    waitcnt_vm<0>();   // retire mask loads so loop vmcnt counting is exact
  }

  f32x4 acc[4][4];
  #pragma unroll
  for (int i = 0; i < 4; i++)
    #pragma unroll
    for (int j = 0; j < 4; j++) acc[i][j] = (f32x4){0.f,0.f,0.f,0.f};

  const int soff = (((((lr & 1) << 2) | q) ^ (lr >> 1)) << 3);  // s*8, lane-const

  auto STAGE = [&](int buf, int kt){
    const _Float16* at = Ahi + ((arow + kt) << 12);
    #pragma unroll
    for (int j = 0; j < 2; j++)
      gload16(at + ((w*2 + j) << 9) + (lane << 3), &sA[buf][(w*2 + j) << 9]);
    if (NSEG == 3){
      const _Float16* alt = Alo + ((arow + kt) << 12);
      const _Float16* bht = Bhi + ((brow + kt) << 12);
      const _Float16* blt = Blo + ((brow + kt) << 12);
      #pragma unroll
      for (int j = 0; j < 2; j++){
        gload16(alt + ((w*2 + j) << 9) + (lane << 3), &sAl[buf][(w*2 + j) << 9]);
        gload16(bht + ((w*2 + j) << 9) + (lane << 3), &sB [buf][(w*2 + j) << 9]);
        gload16(blt + ((w*2 + j) << 9) + (lane << 3), &sBl[buf][(w*2 + j) << 9]);
      }
    } else if (BSEL){
      const _Float16* bht = Bhi + ((brow + kt) << 12);
      const _Float16* blt = Blo + ((brow + kt) << 12);   // mod image
      #pragma unroll
      for (int j = 0; j < 2; j++){
        gload16(bht + ((w*2 + j) << 9) + (lane << 3), &sB [buf][(w*2 + j) << 9]);
        gload16(blt + ((w*2 + j) << 9) + (lane << 3), &sBl[buf][(w*2 + j) << 9]);
      }
    } else {
      const _Float16* bht = Bhi + ((brow + kt) << 12);
      #pragma unroll
      for (int j = 0; j < 2; j++)
        gload16(bht + ((w*2 + j) << 9) + (lane << 3), &sB[buf][(w*2 + j) << 9]);
    }
  };

  STAGE(0, 0);
  int cur = 0;
  for (int kt = 0; kt < nkt; ++kt){
    if (kt + 1 < nkt){ STAGE(cur ^ 1, kt + 1); waitcnt_vm<NLD>(); }
    else             { waitcnt_vm<0>(); }
    __builtin_amdgcn_s_barrier();
    __builtin_amdgcn_sched_barrier(0);

    f16x8 fah[4], fbh[4], fal[4], fbl[4];
    #pragma unroll
    for (int i = 0; i < 4; i++){
      const int ap = ((wr*32 + i*8 + (lr >> 1)) << 6) + soff;
      const int bp = ((wc*32 + i*8 + (lr >> 1)) << 6) + soff;
      fah[i] = *(const f16x8*)&sA[cur][ap];
      if (BSEL) fbh[i] = *(const f16x8*)(bbase[i] + (cur << 12) + bp);
      else      fbh[i] = *(const f16x8*)&sB[cur][bp];
      if (NSEG == 3){
        fal[i] = *(const f16x8*)&sAl[cur][ap];
        fbl[i] = *(const f16x8*)&sBl[cur][bp];
      }
    }
    #pragma unroll
    for (int mi = 0; mi < 4; mi++)
      #pragma unroll
      for (int ni = 0; ni < 4; ni++)
        acc[mi][ni] = __builtin_amdgcn_mfma_f32_16x16x32_f16(fah[mi], fbh[ni], acc[mi][ni], 0,0,0);
    if (NSEG == 3){
      #pragma unroll
      for (int mi = 0; mi < 4; mi++)
        #pragma unroll
        for (int ni = 0; ni < 4; ni++)
          acc[mi][ni] = __builtin_amdgcn_mfma_f32_16x16x32_f16(fal[mi], fbh[ni], acc[mi][ni], 0,0,0);
      #pragma unroll
      for (int mi = 0; mi < 4; mi++)
        #pragma unroll
        for (int ni = 0; ni < 4; ni++)
          acc[mi][ni] = __builtin_amdgcn_mfma_f32_16x16x32_f16(fah[mi], fbl[ni], acc[mi][ni], 0,0,0);
    }
    __builtin_amdgcn_s_barrier();
    cur ^= 1;
  }

  // Epilogue.  C/D layout (m89): col = lane&15, row = (lane>>4)*4 + reg
  if (MODE == MODE_G2){
    __syncthreads();
    for (int i = tid; i < 4096; i += 256) lh[i] = 0;
    __syncthreads();
  }

  #pragma unroll
  for (int ni = 0; ni < 4; ni++){
    const int gc = n0 + wc*64 + ni*16 + lr;
    float bias;
    if (MODE == MODE_UPMOD) bias = mask[(m0 >> 9) * H_DIM + gc] ? bias1[gc] : bias0[gc];
    else                    bias = bias0[gc];
    unsigned colmax = 0u;
    #pragma unroll
    for (int mi = 0; mi < 4; mi++){
      #pragma unroll
      for (int r = 0; r < 4; r++){
        const int gr = m0 + wr*64 + mi*16 + q*4 + r;
        const int cr = gr - c_row_base;
        float v = acc[mi][ni][r] + bias;
        if (MODE == MODE_G1){
          v = fmaxf(v, 0.f);
          _Float16 hh = (_Float16)v;
          size_t d = (img_g32(cr, gc >> 3, N >> 5) << 3) + (gc & 7);
          Chi[d] = hh;
          Clo[d] = (_Float16)(v - (float)hh);
        }
        if (MODE == MODE_UPMOD){
          v = v / (1.f + __expf(-v));
          size_t d = (img_g32(cr, gc >> 3, N >> 5) << 3) + (gc & 7);
          Chi[d] = (_Float16)v;
        }
        if (MODE == MODE_DOWN) C32[(size_t)cr * N + gc] = v;
        if (MODE == MODE_G2){
          unsigned key = lkey(v);
          keys[(size_t)cr * N + gc] = key;
          colmax = max(colmax, key);
          atomicAdd(&lh[key >> 17], 1u);
        }
      }
    }
    if (MODE == MODE_G2)
      atomicMax(&Mkey[(batch_base + (m0 >> 9)) * H_DIM + gc], colmax);
  }

  if (MODE == MODE_G2){
    __syncthreads();
    const int gb = batch_base + (m0 >> 9);
    for (int i = tid; i < 4096; i += 256)
      if (lh[i]) atomicAdd(&hist[(gb << 12) + i], lh[i]);
  }
}

// ---- exact k-th largest per batch: 12-bit hist (from gate2) + candidate refine ----

__global__ __launch_bounds__(256)
void select12(const unsigned* __restrict__ hist, unsigned* __restrict__ b12,
              unsigned* __restrict__ krem, unsigned* __restrict__ ccount, int b0)
{
  const int b = b0 + (int)blockIdx.x;
  __shared__ unsigned part[256];
  const unsigned base = (unsigned)b << 12;
  unsigned s = 0;
  #pragma unroll
  for (int i = 0; i < 16; i++) s += hist[base + threadIdx.x*16 + i];
  part[threadIdx.x] = s;
  __syncthreads();
  if (threadIdx.x == 0){
    unsigned cum = 0; int t = 255;
    for (; t > 0; --t){
      if (cum + part[t] >= K_SEL) break;
      cum += part[t];
    }
    int bin = 15; unsigned kr = K_SEL;
    for (; bin > 0; --bin){
      unsigned c = hist[base + t*16 + bin];
      if (cum + c >= K_SEL) break;
      cum += c;
    }
    kr = K_SEL - cum;
    b12[b] = (unsigned)(t*16 + bin);
    krem[b] = kr;
    ccount[b] = 0;
  }
}

__global__ __launch_bounds__(256)
void collect(const unsigned* __restrict__ keys, const unsigned* __restrict__ b12,
             unsigned* __restrict__ cand, unsigned* __restrict__ ccount, int b0)
{
  const int bl = blockIdx.y;
  const int b  = b0 + bl;
  const unsigned bin = b12[b];
  const uint4* p = (const uint4*)(keys + (size_t)bl*2097152u + (size_t)blockIdx.x*65536u);
  for (int i = threadIdx.x; i < 16384; i += 256){
    uint4 kv = p[i];
    #pragma unroll
    for (int j = 0; j < 4; j++){
      unsigned k = (j==0)?kv.x:(j==1)?kv.y:(j==2)?kv.z:kv.w;
      if ((k >> 17) == bin){
        unsigned idx = atomicAdd(&ccount[b], 1u);
        if (idx < CAND_CAP) cand[((size_t)b << 15) + idx] = k;
      }
    }
  }
}

__global__ __launch_bounds__(256)
void select_exact(const unsigned* __restrict__ cand, const unsigned* __restrict__ ccount,
                  const unsigned* __restrict__ b12, const unsigned* __restrict__ kremA,
                  unsigned* __restrict__ tkey, int b0)
{
  const int b = b0 + (int)blockIdx.x;
  unsigned cc = ccount[b];
  const unsigned n = cc < CAND_CAP ? cc : CAND_CAP;
  __shared__ unsigned h[256];
  __shared__ unsigned sh2[2];
  unsigned prefix = b12[b] << 17;
  unsigned krem = kremA[b];
  const unsigned pm[3]  = {0xFFFE0000u, 0xFFFFFE00u, 0xFFFFFFFEu};
  const int      shs[3] = {9, 1, 0};
  const int      wid[3] = {256, 256, 2};
  for (int pass = 0; pass < 3; ++pass){
    if (threadIdx.x < (unsigned)wid[pass]) h[threadIdx.x] = 0;
    __syncthreads();
    for (unsigned i = threadIdx.x; i < n; i += 256){
      unsigned k = cand[((size_t)b << 15) + i];
      if ((k & pm[pass]) == prefix)
        atomicAdd(&h[(k >> shs[pass]) & (unsigned)(wid[pass]-1)], 1u);
    }
    __syncthreads();
    if (threadIdx.x == 0){
      unsigned cum = 0; int bin = wid[pass]-1;
      for (; bin > 0; --bin){
        unsigned c = h[bin];
        if (cum + c >= krem) break;
        cum += c;
      }
      krem -= cum;
      prefix |= ((unsigned)bin) << shs[pass];
      sh2[0] = prefix; sh2[1] = krem;
    }
    __syncthreads();
    prefix = sh2[0]; krem = sh2[1];
    __syncthreads();
  }
  if (threadIdx.x == 0) tkey[b] = prefix;
}

__global__ __launch_bounds__(256)
void make_mask(const unsigned* __restrict__ Mkey, const unsigned* __restrict__ tkey,
               unsigned* __restrict__ mask){
  const int i = blockIdx.x * 256 + threadIdx.x;   // B*H = 65536
  const int b = i >> 12;
  mask[i] = (Mkey[i] >= tkey[b]) ? 1u : 0u;
}

extern "C" void kernel_launch(void* const* d_in, const int* in_sizes, int n_in,
                              void* d_out, int out_size, void* d_ws, size_t ws_size,
                              hipStream_t stream)
{
  (void)in_sizes; (void)n_in; (void)out_size; (void)ws_size;
  const float* X      = (const float*)d_in[0];
  const float* up_w   = (const float*)d_in[1];
  const float* up_b   = (const float*)d_in[2];
  const float* g1w    = (const float*)d_in[3];
  const float* g1b    = (const float*)d_in[4];
  const float* g2w    = (const float*)d_in[5];
  const float* g2b    = (const float*)d_in[6];
  const float* mod_w  = (const float*)d_in[7];
  const float* mod_b  = (const float*)d_in[8];
  const float* down_w = (const float*)d_in[9];
  const float* down_b = (const float*)d_in[10];
  float* out = (float*)d_out;

  // ws layout (peak ~235 MiB)
  char* ws = (char*)d_ws;
  _Float16* Xhi  = (_Float16*)(ws);
  _Float16* Xlo  = (_Float16*)(ws + (16ull<<20));
  _Float16* G1hi = (_Float16*)(ws + (32ull<<20));
  _Float16* G1lo = (_Float16*)(ws + (40ull<<20));
  _Float16* G2hi = (_Float16*)(ws + (48ull<<20));
  _Float16* G2lo = (_Float16*)(ws + (80ull<<20));
  _Float16* UPhi = (_Float16*)(ws + (112ull<<20));
  _Float16* MODhi= (_Float16*)(ws + (120ull<<20));
  _Float16* DWhi = (_Float16*)(ws + (128ull<<20));
  _Float16* Fhi  = (_Float16*)(ws + (136ull<<20));   // per half [4096][4096]
  _Float16* Flo  = (_Float16*)(ws + (168ull<<20));
  _Float16* Hbuf = (_Float16*)(ws + (136ull<<20));   // reuse after selection
  unsigned* keys = (unsigned*)(ws + (200ull<<20));   // per quarter [2048][4096]
  char* aux = ws + (232ull<<20);
  unsigned* Mkey  = (unsigned*)(aux);                 // 256 KB
  unsigned* maskb = (unsigned*)(aux + 262144);        // 256 KB
  unsigned* hist  = (unsigned*)(aux + 524288);        // 256 KB (16 batches x 4096)
  unsigned* cand  = (unsigned*)(aux + 786432);        // 2 MiB (16 x 32768)
  unsigned* b12   = (unsigned*)(aux + 786432 + 2097152);
  unsigned* krem  = (unsigned*)(aux + 786432 + 2097152 + 64);
  unsigned* ccnt  = (unsigned*)(aux + 786432 + 2097152 + 128);
  unsigned* tkey  = (unsigned*)(aux + 786432 + 2097152 + 192);

  // pack fp32 -> tiled fp16 images
  pack_img<true ><<<4096, 256, 0, stream>>>(X,      Xhi,  Xlo,  7, 32,  1048576);
  pack_img<true ><<<2048, 256, 0, stream>>>(g1w,    G1hi, G1lo, 7, 32,  524288);
  pack_img<true ><<<8192, 256, 0, stream>>>(g2w,    G2hi, G2lo, 9, 128, 2097152);
  pack_img<false><<<2048, 256, 0, stream>>>(up_w,   UPhi, nullptr, 7, 32,  524288);
  pack_img<false><<<2048, 256, 0, stream>>>(mod_w,  MODhi,nullptr, 7, 32,  524288);
  pack_img<false><<<2048, 256, 0, stream>>>(down_w, DWhi, nullptr, 9, 128, 524288);

  hipMemsetAsync(Mkey, 0, 262144, stream);
  hipMemsetAsync(hist, 0, 262144, stream);

  for (int half = 0; half < 2; ++half){
    // gate1 half: F = split(relu(X @ g1w^T + g1b))  [4096 x 4096], K=1024
    gemm_t<MODE_G1><<<dim3(32,32), 256, 0, stream>>>(
        Xhi, Xlo, G1hi, G1lo, g1b, nullptr, nullptr,
        Fhi, Flo, nullptr, nullptr, nullptr, nullptr,
        H_DIM, D_DIM, half*4096, half*4096, 0);
    for (int qd = 0; qd < 2; ++qd){
      const int b0 = half*8 + qd*4;
      // gate2 quarter: keys + Mkey + hist  [2048 x 4096], K=4096
      gemm_t<MODE_G2><<<dim3(32,16), 256, 0, stream>>>(
          Fhi, Flo, G2hi, G2lo, g2b, nullptr, nullptr,
          nullptr, nullptr, nullptr, keys, Mkey, hist,
          H_DIM, H_DIM, qd*2048, qd*2048, half*8);
      select12<<<4, 256, 0, stream>>>(hist, b12, krem, ccnt, b0);
      collect<<<dim3(32,4), 256, 0, stream>>>(keys, b12, cand, ccnt, b0);
      select_exact<<<4, 256, 0, stream>>>(cand, ccnt, b12, krem, tkey, b0);
    }
  }
  make_mask<<<256, 256, 0, stream>>>(Mkey, tkey, maskb);

  // up/mod row-select + silu -> Hbuf image  [8192 x 4096], K=1024
  gemm_t<MODE_UPMOD><<<dim3(32,64), 256, 0, stream>>>(
      Xhi, nullptr, UPhi, MODhi, up_b, mod_b, maskb,
      Hbuf, nullptr, nullptr, nullptr, nullptr, nullptr,
      H_DIM, D_DIM, 0, 0, 0);
  // down: out = Hbuf @ down_w^T + down_b  [8192 x 1024], K=4096
  gemm_t<MODE_DOWN><<<dim3(8,64), 256, 0, stream>>>(
      Hbuf, nullptr, DWhi, nullptr, down_b, nullptr, nullptr,
      nullptr, nullptr, out, nullptr, nullptr, nullptr,
      D_DIM, H_DIM, 0, 0, 0);
}

// Round 7
// 2261.104 us; speedup vs baseline: 1.0051x; 1.0051x over previous
//
#include <hip/hip_runtime.h>
#include <cstdint>

typedef __attribute__((ext_vector_type(4))) _Float16 f16x4;
typedef __attribute__((ext_vector_type(8))) _Float16 f16x8;
typedef __attribute__((ext_vector_type(4))) float f32x4;

#define D_DIM 1024
#define H_DIM 4096
#define BS_ROWS 8192
#define K_SEL 524288u
#define CAND_CAP 32768u

// order-isomorphic fp32 -> uint linear key (monotone; collisions ~2^-22 window, safe)
__device__ __forceinline__ unsigned lkey(float v){
  float u = fmaf(v, 67108864.f, 268435456.f);          // (v+4)*2^26, single rounding
  u = fminf(fmaxf(u, 0.f), 536870911.f);               // clamp to [0, 2^29)
  return (unsigned)u;
}

// async global->LDS, 16B per lane (dest = wave-uniform base + lane*16)
__device__ __forceinline__ void gload16(const _Float16* g, _Float16* l){
  __builtin_amdgcn_global_load_lds(
      (const __attribute__((address_space(1))) void*)g,
      (__attribute__((address_space(3))) void*)l, 16, 0, 0);
}

template<int N> __device__ __forceinline__ void waitcnt_vm(){
  if      constexpr (N == 0) asm volatile("s_waitcnt vmcnt(0)" ::: "memory");
  else if constexpr (N == 4) asm volatile("s_waitcnt vmcnt(4)" ::: "memory");
  else if constexpr (N == 6) asm volatile("s_waitcnt vmcnt(6)" ::: "memory");
  else                       asm volatile("s_waitcnt vmcnt(8)" ::: "memory");
}

// Tiled fp16 image: tiles of 128 rows x 32 halves (8KB, 512 granules of 16B).
// Granule for (row,k8): p=(row&127)>>1, s=((row&1)<<2|(k8&3))^(p&7); index p*8+s.
__device__ __forceinline__ size_t img_g32(int row, int k8, int nkt32){
  int p = (row & 127) >> 1;
  int s = (((row & 1) << 2) | (k8 & 3)) ^ (p & 7);
  return ((size_t)((row >> 7) * nkt32 + (k8 >> 2)) << 9) + (p << 3) + s;
}

template<bool LO>
__global__ __launch_bounds__(256)
void pack_img(const float* __restrict__ W, _Float16* __restrict__ hi,
              _Float16* __restrict__ lo, int k8shift, int nkt32, int total)
{
  int g = blockIdx.x * 256 + threadIdx.x;
  if (g >= total) return;
  int row = g >> k8shift, k8 = g & ((1 << k8shift) - 1);
  const float* src = W + ((size_t)row << (k8shift + 3)) + (k8 << 3);
  float4 f0 = *(const float4*)src, f1 = *(const float4*)(src + 4);
  float ff[8] = {f0.x,f0.y,f0.z,f0.w,f1.x,f1.y,f1.z,f1.w};
  f16x8 hv, lv;
  #pragma unroll
  for (int i = 0; i < 8; i++){
    hv[i] = (_Float16)ff[i];
    if (LO) lv[i] = (_Float16)(ff[i] - (float)hv[i]);
  }
  size_t d = img_g32(row, k8, nkt32) << 3;
  *(f16x8*)&hi[d] = hv;
  if (LO) *(f16x8*)&lo[d] = lv;
}

enum { MODE_G1 = 0, MODE_G2 = 1, MODE_UPMOD = 2, MODE_DOWN = 3 };

// C = A[M,K] * B[N,K]^T + bias.  A/B are tiled fp16 images.
// NSEG==3 (G1,G2): acc = Ahi*Bhi + Alo*Bhi + Ahi*Blo  (~fp32 accuracy).
// Double-buffered LDS, counted vmcnt, raw s_barrier (T3/T4 minimum pipeline).
template<int MODE>
__global__ __launch_bounds__(256)
void gemm_t(const _Float16* __restrict__ Ahi, const _Float16* __restrict__ Alo,
            const _Float16* __restrict__ Bhi, const _Float16* __restrict__ Blo,
            const float* __restrict__ bias0, const float* __restrict__ bias1,
            const unsigned* __restrict__ mask,
            _Float16* __restrict__ Chi, _Float16* __restrict__ Clo,
            float* __restrict__ C32,
            unsigned* __restrict__ keys, unsigned* __restrict__ Mkey,
            unsigned* __restrict__ hist,
            int N, int K, int m_img_base, int c_row_base, int batch_base)
{
  constexpr int NSEG = (MODE == MODE_G1 || MODE == MODE_G2) ? 3 : 1;
  constexpr bool BSEL = (MODE == MODE_UPMOD);
  constexpr int NLD = (NSEG == 3) ? 8 : (BSEL ? 6 : 4);
  __shared__ __align__(16) _Float16 sA [2][4096];
  __shared__ __align__(16) _Float16 sB [2][4096];
  __shared__ __align__(16) _Float16 sAl[NSEG == 3 ? 2 : 1][NSEG == 3 ? 4096 : 8];
  __shared__ __align__(16) _Float16 sBl[(NSEG == 3 || BSEL) ? 2 : 1][(NSEG == 3 || BSEL) ? 4096 : 8];
  __shared__ unsigned lh[MODE == MODE_G2 ? 4096 : 1];

  // XCD-aware block swizzle (all grids have nwg % 8 == 0)
  const int nbx = gridDim.x;
  int wg = blockIdx.y * nbx + blockIdx.x;
  const int nwg = nbx * gridDim.y;
  wg = (wg & 7) * (nwg >> 3) + (wg >> 3);
  const int bx = wg % nbx, by = wg / nbx;

  const int tid = threadIdx.x;
  const int lane = tid & 63;
  const int w  = tid >> 6;
  const int wr = w >> 1, wc = w & 1;
  const int lr = lane & 15;
  const int q  = lane >> 4;

  const int m0 = m_img_base + by * 128;
  const int n0 = bx * 128;
  const int nkt = K >> 5;
  const size_t arow = (size_t)(m0 >> 7) * nkt;
  const size_t brow = (size_t)(n0 >> 7) * nkt;

  // UPMOD: per-fragment-row B select (up vs mod), resolved before the loop
  const _Float16* bbase[4];
  if (BSEL){
    const int bb = m0 >> 9;
    #pragma unroll
    for (int i = 0; i < 4; i++){
      int row = wc*64 + i*16 + lr;
      bbase[i] = mask[bb * H_DIM + n0 + row] ? &sBl[0][0] : &sB[0][0];
    }
    waitcnt_vm<0>();   // retire mask loads so loop vmcnt counting is exact
  }

  f32x4 acc[4][4];
  #pragma unroll
  for (int i = 0; i < 4; i++)
    #pragma unroll
    for (int j = 0; j < 4; j++) acc[i][j] = (f32x4){0.f,0.f,0.f,0.f};

  const int soff = (((((lr & 1) << 2) | q) ^ (lr >> 1)) << 3);  // s*8, lane-const

  auto STAGE = [&](int buf, int kt){
    const _Float16* at = Ahi + ((arow + kt) << 12);
    #pragma unroll
    for (int j = 0; j < 2; j++)
      gload16(at + ((w*2 + j) << 9) + (lane << 3), &sA[buf][(w*2 + j) << 9]);
    if (NSEG == 3){
      const _Float16* alt = Alo + ((arow + kt) << 12);
      const _Float16* bht = Bhi + ((brow + kt) << 12);
      const _Float16* blt = Blo + ((brow + kt) << 12);
      #pragma unroll
      for (int j = 0; j < 2; j++){
        gload16(alt + ((w*2 + j) << 9) + (lane << 3), &sAl[buf][(w*2 + j) << 9]);
        gload16(bht + ((w*2 + j) << 9) + (lane << 3), &sB [buf][(w*2 + j) << 9]);
        gload16(blt + ((w*2 + j) << 9) + (lane << 3), &sBl[buf][(w*2 + j) << 9]);
      }
    } else if (BSEL){
      const _Float16* bht = Bhi + ((brow + kt) << 12);
      const _Float16* blt = Blo + ((brow + kt) << 12);   // mod image
      #pragma unroll
      for (int j = 0; j < 2; j++){
        gload16(bht + ((w*2 + j) << 9) + (lane << 3), &sB [buf][(w*2 + j) << 9]);
        gload16(blt + ((w*2 + j) << 9) + (lane << 3), &sBl[buf][(w*2 + j) << 9]);
      }
    } else {
      const _Float16* bht = Bhi + ((brow + kt) << 12);
      #pragma unroll
      for (int j = 0; j < 2; j++)
        gload16(bht + ((w*2 + j) << 9) + (lane << 3), &sB[buf][(w*2 + j) << 9]);
    }
  };

  STAGE(0, 0);
  int cur = 0;
  for (int kt = 0; kt < nkt; ++kt){
    if (kt + 1 < nkt){ STAGE(cur ^ 1, kt + 1); waitcnt_vm<NLD>(); }
    else             { waitcnt_vm<0>(); }
    __builtin_amdgcn_s_barrier();
    __builtin_amdgcn_sched_barrier(0);

    f16x8 fah[4], fbh[4], fal[4], fbl[4];
    #pragma unroll
    for (int i = 0; i < 4; i++){
      const int ap = ((wr*32 + i*8 + (lr >> 1)) << 6) + soff;
      const int bp = ((wc*32 + i*8 + (lr >> 1)) << 6) + soff;
      fah[i] = *(const f16x8*)&sA[cur][ap];
      if (BSEL) fbh[i] = *(const f16x8*)(bbase[i] + (cur << 12) + bp);
      else      fbh[i] = *(const f16x8*)&sB[cur][bp];
      if (NSEG == 3){
        fal[i] = *(const f16x8*)&sAl[cur][ap];
        fbl[i] = *(const f16x8*)&sBl[cur][bp];
      }
    }
    #pragma unroll
    for (int mi = 0; mi < 4; mi++)
      #pragma unroll
      for (int ni = 0; ni < 4; ni++)
        acc[mi][ni] = __builtin_amdgcn_mfma_f32_16x16x32_f16(fah[mi], fbh[ni], acc[mi][ni], 0,0,0);
    if (NSEG == 3){
      #pragma unroll
      for (int mi = 0; mi < 4; mi++)
        #pragma unroll
        for (int ni = 0; ni < 4; ni++)
          acc[mi][ni] = __builtin_amdgcn_mfma_f32_16x16x32_f16(fal[mi], fbh[ni], acc[mi][ni], 0,0,0);
      #pragma unroll
      for (int mi = 0; mi < 4; mi++)
        #pragma unroll
        for (int ni = 0; ni < 4; ni++)
          acc[mi][ni] = __builtin_amdgcn_mfma_f32_16x16x32_f16(fah[mi], fbl[ni], acc[mi][ni], 0,0,0);
    }
    __builtin_amdgcn_s_barrier();
    cur ^= 1;
  }

  // Epilogue.  C/D layout (m89): col = lane&15, row = (lane>>4)*4 + reg
  if (MODE == MODE_G2){
    __syncthreads();
    for (int i = tid; i < 4096; i += 256) lh[i] = 0;
    __syncthreads();
  }

  #pragma unroll
  for (int ni = 0; ni < 4; ni++){
    const int gc = n0 + wc*64 + ni*16 + lr;
    float bias;
    if (MODE == MODE_UPMOD) bias = mask[(m0 >> 9) * H_DIM + gc] ? bias1[gc] : bias0[gc];
    else                    bias = bias0[gc];
    unsigned colmax = 0u;
    #pragma unroll
    for (int mi = 0; mi < 4; mi++){
      #pragma unroll
      for (int r = 0; r < 4; r++){
        const int gr = m0 + wr*64 + mi*16 + q*4 + r;
        const int cr = gr - c_row_base;
        float v = acc[mi][ni][r] + bias;
        if (MODE == MODE_G1){
          v = fmaxf(v, 0.f);
          _Float16 hh = (_Float16)v;
          size_t d = (img_g32(cr, gc >> 3, N >> 5) << 3) + (gc & 7);
          Chi[d] = hh;
          Clo[d] = (_Float16)(v - (float)hh);
        }
        if (MODE == MODE_UPMOD){
          v = v / (1.f + __expf(-v));
          size_t d = (img_g32(cr, gc >> 3, N >> 5) << 3) + (gc & 7);
          Chi[d] = (_Float16)v;
        }
        if (MODE == MODE_DOWN) C32[(size_t)cr * N + gc] = v;
        if (MODE == MODE_G2){
          unsigned key = lkey(v);
          keys[(size_t)cr * N + gc] = key;
          colmax = max(colmax, key);
          atomicAdd(&lh[key >> 17], 1u);
        }
      }
    }
    if (MODE == MODE_G2)
      atomicMax(&Mkey[(batch_base + (m0 >> 9)) * H_DIM + gc], colmax);
  }

  if (MODE == MODE_G2){
    __syncthreads();
    const int gb = batch_base + (m0 >> 9);
    for (int i = tid; i < 4096; i += 256)
      if (lh[i]) atomicAdd(&hist[(gb << 12) + i], lh[i]);
  }
}

// ---- exact k-th largest per batch: 12-bit hist (from gate2) + candidate refine ----

__global__ __launch_bounds__(256)
void select12(const unsigned* __restrict__ hist, unsigned* __restrict__ b12,
              unsigned* __restrict__ krem, unsigned* __restrict__ ccount, int b0)
{
  const int b = b0 + (int)blockIdx.x;
  __shared__ unsigned part[256];
  const unsigned base = (unsigned)b << 12;
  unsigned s = 0;
  #pragma unroll
  for (int i = 0; i < 16; i++) s += hist[base + threadIdx.x*16 + i];
  part[threadIdx.x] = s;
  __syncthreads();
  if (threadIdx.x == 0){
    unsigned cum = 0; int t = 255;
    for (; t > 0; --t){
      if (cum + part[t] >= K_SEL) break;
      cum += part[t];
    }
    int bin = 15; unsigned kr = K_SEL;
    for (; bin > 0; --bin){
      unsigned c = hist[base + t*16 + bin];
      if (cum + c >= K_SEL) break;
      cum += c;
    }
    kr = K_SEL - cum;
    b12[b] = (unsigned)(t*16 + bin);
    krem[b] = kr;
    ccount[b] = 0;
  }
}

// 1024 WGs; each thread batch-loads 8 independent uint4 (MLP fix: r6 had ~1
// outstanding load/wave -> 74 GB/s; 8 outstanding -> HBM-bound)
__global__ __launch_bounds__(256)
void collect(const unsigned* __restrict__ keys, const unsigned* __restrict__ b12,
             unsigned* __restrict__ cand, unsigned* __restrict__ ccount, int b0)
{
  const int bl = blockIdx.y;
  const int b  = b0 + bl;
  const unsigned bin = b12[b];
  const uint4* p = (const uint4*)(keys + (size_t)bl*2097152u + (size_t)blockIdx.x*8192u);
  uint4 kv[8];
  #pragma unroll
  for (int j = 0; j < 8; j++) kv[j] = p[threadIdx.x + j*256];
  #pragma unroll
  for (int j = 0; j < 8; j++){
    #pragma unroll
    for (int e = 0; e < 4; e++){
      unsigned k = (e==0)?kv[j].x:(e==1)?kv[j].y:(e==2)?kv[j].z:kv[j].w;
      if ((k >> 17) == bin){
        unsigned idx = atomicAdd(&ccount[b], 1u);
        if (idx < CAND_CAP) cand[((size_t)b << 15) + idx] = k;
      }
    }
  }
}

__global__ __launch_bounds__(256)
void select_exact(const unsigned* __restrict__ cand, const unsigned* __restrict__ ccount,
                  const unsigned* __restrict__ b12, const unsigned* __restrict__ kremA,
                  unsigned* __restrict__ tkey, int b0)
{
  const int b = b0 + (int)blockIdx.x;
  unsigned cc = ccount[b];
  const unsigned n = cc < CAND_CAP ? cc : CAND_CAP;
  __shared__ unsigned h[256];
  __shared__ unsigned sh2[2];
  unsigned prefix = b12[b] << 17;
  unsigned krem = kremA[b];
  const unsigned pm[3]  = {0xFFFE0000u, 0xFFFFFE00u, 0xFFFFFFFEu};
  const int      shs[3] = {9, 1, 0};
  const int      wid[3] = {256, 256, 2};
  for (int pass = 0; pass < 3; ++pass){
    if (threadIdx.x < (unsigned)wid[pass]) h[threadIdx.x] = 0;
    __syncthreads();
    for (unsigned i = threadIdx.x; i < n; i += 256){
      unsigned k = cand[((size_t)b << 15) + i];
      if ((k & pm[pass]) == prefix)
        atomicAdd(&h[(k >> shs[pass]) & (unsigned)(wid[pass]-1)], 1u);
    }
    __syncthreads();
    if (threadIdx.x == 0){
      unsigned cum = 0; int bin = wid[pass]-1;
      for (; bin > 0; --bin){
        unsigned c = h[bin];
        if (cum + c >= krem) break;
        cum += c;
      }
      krem -= cum;
      prefix |= ((unsigned)bin) << shs[pass];
      sh2[0] = prefix; sh2[1] = krem;
    }
    __syncthreads();
    prefix = sh2[0]; krem = sh2[1];
    __syncthreads();
  }
  if (threadIdx.x == 0) tkey[b] = prefix;
}

__global__ __launch_bounds__(256)
void make_mask(const unsigned* __restrict__ Mkey, const unsigned* __restrict__ tkey,
               unsigned* __restrict__ mask){
  const int i = blockIdx.x * 256 + threadIdx.x;   // B*H = 65536
  const int b = i >> 12;
  mask[i] = (Mkey[i] >= tkey[b]) ? 1u : 0u;
}

extern "C" void kernel_launch(void* const* d_in, const int* in_sizes, int n_in,
                              void* d_out, int out_size, void* d_ws, size_t ws_size,
                              hipStream_t stream)
{
  (void)in_sizes; (void)n_in; (void)out_size; (void)ws_size;
  const float* X      = (const float*)d_in[0];
  const float* up_w   = (const float*)d_in[1];
  const float* up_b   = (const float*)d_in[2];
  const float* g1w    = (const float*)d_in[3];
  const float* g1b    = (const float*)d_in[4];
  const float* g2w    = (const float*)d_in[5];
  const float* g2b    = (const float*)d_in[6];
  const float* mod_w  = (const float*)d_in[7];
  const float* mod_b  = (const float*)d_in[8];
  const float* down_w = (const float*)d_in[9];
  const float* down_b = (const float*)d_in[10];
  float* out = (float*)d_out;

  // ws layout (peak ~235 MiB)
  char* ws = (char*)d_ws;
  _Float16* Xhi  = (_Float16*)(ws);
  _Float16* Xlo  = (_Float16*)(ws + (16ull<<20));
  _Float16* G1hi = (_Float16*)(ws + (32ull<<20));
  _Float16* G1lo = (_Float16*)(ws + (40ull<<20));
  _Float16* G2hi = (_Float16*)(ws + (48ull<<20));
  _Float16* G2lo = (_Float16*)(ws + (80ull<<20));
  _Float16* UPhi = (_Float16*)(ws + (112ull<<20));
  _Float16* MODhi= (_Float16*)(ws + (120ull<<20));
  _Float16* DWhi = (_Float16*)(ws + (128ull<<20));
  _Float16* Fhi  = (_Float16*)(ws + (136ull<<20));   // per half [4096][4096]
  _Float16* Flo  = (_Float16*)(ws + (168ull<<20));
  _Float16* Hbuf = (_Float16*)(ws + (136ull<<20));   // reuse after selection
  unsigned* keys = (unsigned*)(ws + (200ull<<20));   // per quarter [2048][4096]
  char* aux = ws + (232ull<<20);
  unsigned* Mkey  = (unsigned*)(aux);                 // 256 KB
  unsigned* maskb = (unsigned*)(aux + 262144);        // 256 KB
  unsigned* hist  = (unsigned*)(aux + 524288);        // 256 KB (16 batches x 4096)
  unsigned* cand  = (unsigned*)(aux + 786432);        // 2 MiB (16 x 32768)
  unsigned* b12   = (unsigned*)(aux + 786432 + 2097152);
  unsigned* krem  = (unsigned*)(aux + 786432 + 2097152 + 64);
  unsigned* ccnt  = (unsigned*)(aux + 786432 + 2097152 + 128);
  unsigned* tkey  = (unsigned*)(aux + 786432 + 2097152 + 192);

  // pack fp32 -> tiled fp16 images
  pack_img<true ><<<4096, 256, 0, stream>>>(X,      Xhi,  Xlo,  7, 32,  1048576);
  pack_img<true ><<<2048, 256, 0, stream>>>(g1w,    G1hi, G1lo, 7, 32,  524288);
  pack_img<true ><<<8192, 256, 0, stream>>>(g2w,    G2hi, G2lo, 9, 128, 2097152);
  pack_img<false><<<2048, 256, 0, stream>>>(up_w,   UPhi, nullptr, 7, 32,  524288);
  pack_img<false><<<2048, 256, 0, stream>>>(mod_w,  MODhi,nullptr, 7, 32,  524288);
  pack_img<false><<<2048, 256, 0, stream>>>(down_w, DWhi, nullptr, 9, 128, 524288);

  hipMemsetAsync(Mkey, 0, 262144, stream);
  hipMemsetAsync(hist, 0, 262144, stream);

  for (int half = 0; half < 2; ++half){
    // gate1 half: F = split(relu(X @ g1w^T + g1b))  [4096 x 4096], K=1024
    gemm_t<MODE_G1><<<dim3(32,32), 256, 0, stream>>>(
        Xhi, Xlo, G1hi, G1lo, g1b, nullptr, nullptr,
        Fhi, Flo, nullptr, nullptr, nullptr, nullptr,
        H_DIM, D_DIM, half*4096, half*4096, 0);
    for (int qd = 0; qd < 2; ++qd){
      const int b0 = half*8 + qd*4;
      // gate2 quarter: keys + Mkey + hist  [2048 x 4096], K=4096
      gemm_t<MODE_G2><<<dim3(32,16), 256, 0, stream>>>(
          Fhi, Flo, G2hi, G2lo, g2b, nullptr, nullptr,
          nullptr, nullptr, nullptr, keys, Mkey, hist,
          H_DIM, H_DIM, qd*2048, qd*2048, half*8);
      select12<<<4, 256, 0, stream>>>(hist, b12, krem, ccnt, b0);
      collect<<<dim3(256,4), 256, 0, stream>>>(keys, b12, cand, ccnt, b0);
      select_exact<<<4, 256, 0, stream>>>(cand, ccnt, b12, krem, tkey, b0);
    }
  }
  make_mask<<<256, 256, 0, stream>>>(Mkey, tkey, maskb);

  // up/mod row-select + silu -> Hbuf image  [8192 x 4096], K=1024
  gemm_t<MODE_UPMOD><<<dim3(32,64), 256, 0, stream>>>(
      Xhi, nullptr, UPhi, MODhi, up_b, mod_b, maskb,
      Hbuf, nullptr, nullptr, nullptr, nullptr, nullptr,
      H_DIM, D_DIM, 0, 0, 0);
  // down: out = Hbuf @ down_w^T + down_b  [8192 x 1024], K=4096
  gemm_t<MODE_DOWN><<<dim3(8,64), 256, 0, stream>>>(
      Hbuf, nullptr, DWhi, nullptr, down_b, nullptr, nullptr,
      nullptr, nullptr, out, nullptr, nullptr, nullptr,
      D_DIM, H_DIM, 0, 0, 0);
}

// Round 8
// 1390.662 us; speedup vs baseline: 1.6342x; 1.6259x over previous
//
#include <hip/hip_runtime.h>
#include <cstdint>

typedef __attribute__((ext_vector_type(4))) _Float16 f16x4;
typedef __attribute__((ext_vector_type(8))) _Float16 f16x8;
typedef __attribute__((ext_vector_type(4))) float f32x4;

#define D_DIM 1024
#define H_DIM 4096
#define BS_ROWS 8192
#define K_SEL 524288u
#define CAND_CAP 32768u

// order-isomorphic fp32 -> uint linear key (monotone; collisions ~2^-22 window, safe)
__device__ __forceinline__ unsigned lkey(float v){
  float u = fmaf(v, 67108864.f, 268435456.f);          // (v+4)*2^26, single rounding
  u = fminf(fmaxf(u, 0.f), 536870911.f);               // clamp to [0, 2^29)
  return (unsigned)u;
}

// async global->LDS, 16B per lane (dest = wave-uniform base + lane*16)
__device__ __forceinline__ void gload16(const _Float16* g, _Float16* l){
  __builtin_amdgcn_global_load_lds(
      (const __attribute__((address_space(1))) void*)g,
      (__attribute__((address_space(3))) void*)l, 16, 0, 0);
}

template<int N> __device__ __forceinline__ void waitcnt_vm(){
  if      constexpr (N == 0) asm volatile("s_waitcnt vmcnt(0)" ::: "memory");
  else if constexpr (N == 4) asm volatile("s_waitcnt vmcnt(4)" ::: "memory");
  else if constexpr (N == 6) asm volatile("s_waitcnt vmcnt(6)" ::: "memory");
  else                       asm volatile("s_waitcnt vmcnt(8)" ::: "memory");
}

// Tiled fp16 image: tiles of 128 rows x 32 halves (8KB, 512 granules of 16B).
// Granule for (row,k8): p=(row&127)>>1, s=((row&1)<<2|(k8&3))^(p&7); index p*8+s.
__device__ __forceinline__ size_t img_g32(int row, int k8, int nkt32){
  int p = (row & 127) >> 1;
  int s = (((row & 1) << 2) | (k8 & 3)) ^ (p & 7);
  return ((size_t)((row >> 7) * nkt32 + (k8 >> 2)) << 9) + (p << 3) + s;
}

template<bool LO>
__global__ __launch_bounds__(256)
void pack_img(const float* __restrict__ W, _Float16* __restrict__ hi,
              _Float16* __restrict__ lo, int k8shift, int nkt32, int total)
{
  int g = blockIdx.x * 256 + threadIdx.x;
  if (g >= total) return;
  int row = g >> k8shift, k8 = g & ((1 << k8shift) - 1);
  const float* src = W + ((size_t)row << (k8shift + 3)) + (k8 << 3);
  float4 f0 = *(const float4*)src, f1 = *(const float4*)(src + 4);
  float ff[8] = {f0.x,f0.y,f0.z,f0.w,f1.x,f1.y,f1.z,f1.w};
  f16x8 hv, lv;
  #pragma unroll
  for (int i = 0; i < 8; i++){
    hv[i] = (_Float16)ff[i];
    if (LO) lv[i] = (_Float16)(ff[i] - (float)hv[i]);
  }
  size_t d = img_g32(row, k8, nkt32) << 3;
  *(f16x8*)&hi[d] = hv;
  if (LO) *(f16x8*)&lo[d] = lv;
}

enum { MODE_G1 = 0, MODE_G2 = 1, MODE_UPMOD = 2, MODE_DOWN = 3 };

// C = A[M,K] * B[N,K]^T + bias.  A/B are tiled fp16 images.
// NSEG==3 (G1,G2): acc = Ahi*Bhi + Alo*Bhi + Ahi*Blo  (~fp32 accuracy).
// Double-buffered LDS, counted vmcnt, raw s_barrier (T3/T4 minimum pipeline).
template<int MODE>
__global__ __launch_bounds__(256)
void gemm_t(const _Float16* __restrict__ Ahi, const _Float16* __restrict__ Alo,
            const _Float16* __restrict__ Bhi, const _Float16* __restrict__ Blo,
            const float* __restrict__ bias0, const float* __restrict__ bias1,
            const unsigned* __restrict__ mask,
            _Float16* __restrict__ Chi, _Float16* __restrict__ Clo,
            float* __restrict__ C32,
            unsigned* __restrict__ keys, unsigned* __restrict__ Mkey,
            unsigned* __restrict__ hist,
            int N, int K, int m_img_base, int c_row_base, int batch_base)
{
  constexpr int NSEG = (MODE == MODE_G1 || MODE == MODE_G2) ? 3 : 1;
  constexpr bool BSEL = (MODE == MODE_UPMOD);
  constexpr int NLD = (NSEG == 3) ? 8 : (BSEL ? 6 : 4);
  __shared__ __align__(16) _Float16 sA [2][4096];
  __shared__ __align__(16) _Float16 sB [2][4096];
  __shared__ __align__(16) _Float16 sAl[NSEG == 3 ? 2 : 1][NSEG == 3 ? 4096 : 8];
  __shared__ __align__(16) _Float16 sBl[(NSEG == 3 || BSEL) ? 2 : 1][(NSEG == 3 || BSEL) ? 4096 : 8];
  __shared__ unsigned lh[MODE == MODE_G2 ? 4096 : 1];

  // XCD-aware block swizzle (all grids have nwg % 8 == 0)
  const int nbx = gridDim.x;
  int wg = blockIdx.y * nbx + blockIdx.x;
  const int nwg = nbx * gridDim.y;
  wg = (wg & 7) * (nwg >> 3) + (wg >> 3);
  const int bx = wg % nbx, by = wg / nbx;

  const int tid = threadIdx.x;
  const int lane = tid & 63;
  const int w  = tid >> 6;
  const int wr = w >> 1, wc = w & 1;
  const int lr = lane & 15;
  const int q  = lane >> 4;

  const int m0 = m_img_base + by * 128;
  const int n0 = bx * 128;
  const int nkt = K >> 5;
  const size_t arow = (size_t)(m0 >> 7) * nkt;
  const size_t brow = (size_t)(n0 >> 7) * nkt;

  // UPMOD: per-fragment-row B select (up vs mod), resolved before the loop
  const _Float16* bbase[4];
  if (BSEL){
    const int bb = m0 >> 9;
    #pragma unroll
    for (int i = 0; i < 4; i++){
      int row = wc*64 + i*16 + lr;
      bbase[i] = mask[bb * H_DIM + n0 + row] ? &sBl[0][0] : &sB[0][0];
    }
    waitcnt_vm<0>();   // retire mask loads so loop vmcnt counting is exact
  }

  f32x4 acc[4][4];
  #pragma unroll
  for (int i = 0; i < 4; i++)
    #pragma unroll
    for (int j = 0; j < 4; j++) acc[i][j] = (f32x4){0.f,0.f,0.f,0.f};

  const int soff = (((((lr & 1) << 2) | q) ^ (lr >> 1)) << 3);  // s*8, lane-const

  auto STAGE = [&](int buf, int kt){
    const _Float16* at = Ahi + ((arow + kt) << 12);
    #pragma unroll
    for (int j = 0; j < 2; j++)
      gload16(at + ((w*2 + j) << 9) + (lane << 3), &sA[buf][(w*2 + j) << 9]);
    if (NSEG == 3){
      const _Float16* alt = Alo + ((arow + kt) << 12);
      const _Float16* bht = Bhi + ((brow + kt) << 12);
      const _Float16* blt = Blo + ((brow + kt) << 12);
      #pragma unroll
      for (int j = 0; j < 2; j++){
        gload16(alt + ((w*2 + j) << 9) + (lane << 3), &sAl[buf][(w*2 + j) << 9]);
        gload16(bht + ((w*2 + j) << 9) + (lane << 3), &sB [buf][(w*2 + j) << 9]);
        gload16(blt + ((w*2 + j) << 9) + (lane << 3), &sBl[buf][(w*2 + j) << 9]);
      }
    } else if (BSEL){
      const _Float16* bht = Bhi + ((brow + kt) << 12);
      const _Float16* blt = Blo + ((brow + kt) << 12);   // mod image
      #pragma unroll
      for (int j = 0; j < 2; j++){
        gload16(bht + ((w*2 + j) << 9) + (lane << 3), &sB [buf][(w*2 + j) << 9]);
        gload16(blt + ((w*2 + j) << 9) + (lane << 3), &sBl[buf][(w*2 + j) << 9]);
      }
    } else {
      const _Float16* bht = Bhi + ((brow + kt) << 12);
      #pragma unroll
      for (int j = 0; j < 2; j++)
        gload16(bht + ((w*2 + j) << 9) + (lane << 3), &sB[buf][(w*2 + j) << 9]);
    }
  };

  STAGE(0, 0);
  int cur = 0;
  for (int kt = 0; kt < nkt; ++kt){
    if (kt + 1 < nkt){ STAGE(cur ^ 1, kt + 1); waitcnt_vm<NLD>(); }
    else             { waitcnt_vm<0>(); }
    __builtin_amdgcn_s_barrier();
    __builtin_amdgcn_sched_barrier(0);

    f16x8 fah[4], fbh[4], fal[4], fbl[4];
    #pragma unroll
    for (int i = 0; i < 4; i++){
      const int ap = ((wr*32 + i*8 + (lr >> 1)) << 6) + soff;
      const int bp = ((wc*32 + i*8 + (lr >> 1)) << 6) + soff;
      fah[i] = *(const f16x8*)&sA[cur][ap];
      if (BSEL) fbh[i] = *(const f16x8*)(bbase[i] + (cur << 12) + bp);
      else      fbh[i] = *(const f16x8*)&sB[cur][bp];
      if (NSEG == 3){
        fal[i] = *(const f16x8*)&sAl[cur][ap];
        fbl[i] = *(const f16x8*)&sBl[cur][bp];
      }
    }
    #pragma unroll
    for (int mi = 0; mi < 4; mi++)
      #pragma unroll
      for (int ni = 0; ni < 4; ni++)
        acc[mi][ni] = __builtin_amdgcn_mfma_f32_16x16x32_f16(fah[mi], fbh[ni], acc[mi][ni], 0,0,0);
    if (NSEG == 3){
      #pragma unroll
      for (int mi = 0; mi < 4; mi++)
        #pragma unroll
        for (int ni = 0; ni < 4; ni++)
          acc[mi][ni] = __builtin_amdgcn_mfma_f32_16x16x32_f16(fal[mi], fbh[ni], acc[mi][ni], 0,0,0);
      #pragma unroll
      for (int mi = 0; mi < 4; mi++)
        #pragma unroll
        for (int ni = 0; ni < 4; ni++)
          acc[mi][ni] = __builtin_amdgcn_mfma_f32_16x16x32_f16(fah[mi], fbl[ni], acc[mi][ni], 0,0,0);
    }
    __builtin_amdgcn_s_barrier();
    cur ^= 1;
  }

  // Epilogue.  C/D layout (m89): col = lane&15, row = (lane>>4)*4 + reg
  if (MODE == MODE_G2){
    __syncthreads();
    for (int i = tid; i < 4096; i += 256) lh[i] = 0;
    __syncthreads();
  }

  #pragma unroll
  for (int ni = 0; ni < 4; ni++){
    const int gc = n0 + wc*64 + ni*16 + lr;
    float bias;
    if (MODE == MODE_UPMOD) bias = mask[(m0 >> 9) * H_DIM + gc] ? bias1[gc] : bias0[gc];
    else                    bias = bias0[gc];
    unsigned colmax = 0u;
    #pragma unroll
    for (int mi = 0; mi < 4; mi++){
      #pragma unroll
      for (int r = 0; r < 4; r++){
        const int gr = m0 + wr*64 + mi*16 + q*4 + r;
        const int cr = gr - c_row_base;
        float v = acc[mi][ni][r] + bias;
        if (MODE == MODE_G1){
          v = fmaxf(v, 0.f);
          _Float16 hh = (_Float16)v;
          size_t d = (img_g32(cr, gc >> 3, N >> 5) << 3) + (gc & 7);
          Chi[d] = hh;
          Clo[d] = (_Float16)(v - (float)hh);
        }
        if (MODE == MODE_UPMOD){
          v = v / (1.f + __expf(-v));
          size_t d = (img_g32(cr, gc >> 3, N >> 5) << 3) + (gc & 7);
          Chi[d] = (_Float16)v;
        }
        if (MODE == MODE_DOWN) C32[(size_t)cr * N + gc] = v;
        if (MODE == MODE_G2){
          unsigned key = lkey(v);
          keys[(size_t)cr * N + gc] = key;
          colmax = max(colmax, key);
          atomicAdd(&lh[key >> 17], 1u);
        }
      }
    }
    if (MODE == MODE_G2)
      atomicMax(&Mkey[(batch_base + (m0 >> 9)) * H_DIM + gc], colmax);
  }

  if (MODE == MODE_G2){
    __syncthreads();
    const int gb = batch_base + (m0 >> 9);
    for (int i = tid; i < 4096; i += 256)
      if (lh[i]) atomicAdd(&hist[(gb << 12) + i], lh[i]);
  }
}

// ---- exact k-th largest per batch: 12-bit hist (from gate2) + candidate refine ----

__global__ __launch_bounds__(256)
void select12(const unsigned* __restrict__ hist, unsigned* __restrict__ b12,
              unsigned* __restrict__ krem, unsigned* __restrict__ ccount, int b0)
{
  const int b = b0 + (int)blockIdx.x;
  __shared__ unsigned part[256];
  const unsigned base = (unsigned)b << 12;
  unsigned s = 0;
  #pragma unroll
  for (int i = 0; i < 16; i++) s += hist[base + threadIdx.x*16 + i];
  part[threadIdx.x] = s;
  __syncthreads();
  if (threadIdx.x == 0){
    unsigned cum = 0; int t = 255;
    for (; t > 0; --t){
      if (cum + part[t] >= K_SEL) break;
      cum += part[t];
    }
    int bin = 15; unsigned kr = K_SEL;
    for (; bin > 0; --bin){
      unsigned c = hist[base + t*16 + bin];
      if (cum + c >= K_SEL) break;
      cum += c;
    }
    kr = K_SEL - cum;
    b12[b] = (unsigned)(t*16 + bin);
    krem[b] = kr;
    ccount[b] = 0;
  }
}

// r7 diagnosis: ~5K same-address global atomicAdds serialized (~50ns each) = 237us.
// Fix: LDS-buffered match gather + ONE global atomic per WG (256/address = ~13us).
__global__ __launch_bounds__(256)
void collect(const unsigned* __restrict__ keys, const unsigned* __restrict__ b12,
             unsigned* __restrict__ cand, unsigned* __restrict__ ccount, int b0)
{
  __shared__ unsigned cbuf[1024];
  __shared__ unsigned lcnt, gbase;
  const int bl = blockIdx.y;
  const int b  = b0 + bl;
  const unsigned bin = b12[b];
  if (threadIdx.x == 0) lcnt = 0;
  __syncthreads();
  const uint4* p = (const uint4*)(keys + (size_t)bl*2097152u + (size_t)blockIdx.x*8192u);
  uint4 kv[8];
  #pragma unroll
  for (int j = 0; j < 8; j++) kv[j] = p[threadIdx.x + j*256];
  #pragma unroll
  for (int j = 0; j < 8; j++){
    #pragma unroll
    for (int e = 0; e < 4; e++){
      unsigned k = (e==0)?kv[j].x:(e==1)?kv[j].y:(e==2)?kv[j].z:kv[j].w;
      if ((k >> 17) == bin){
        unsigned idx = atomicAdd(&lcnt, 1u);     // LDS atomic: fast, distributed
        if (idx < 1024u) cbuf[idx] = k;
      }
    }
  }
  __syncthreads();
  const unsigned n = lcnt < 1024u ? lcnt : 1024u;
  if (threadIdx.x == 0) gbase = atomicAdd(&ccount[b], n);   // 1 global atomic per WG
  __syncthreads();
  const unsigned gb = gbase;
  for (unsigned i = threadIdx.x; i < n; i += 256){
    unsigned dst = gb + i;
    if (dst < CAND_CAP) cand[((size_t)b << 15) + dst] = cbuf[i];
  }
}

__global__ __launch_bounds__(256)
void select_exact(const unsigned* __restrict__ cand, const unsigned* __restrict__ ccount,
                  const unsigned* __restrict__ b12, const unsigned* __restrict__ kremA,
                  unsigned* __restrict__ tkey, int b0)
{
  const int b = b0 + (int)blockIdx.x;
  unsigned cc = ccount[b];
  const unsigned n = cc < CAND_CAP ? cc : CAND_CAP;
  __shared__ unsigned h[256];
  __shared__ unsigned sh2[2];
  unsigned prefix = b12[b] << 17;
  unsigned krem = kremA[b];
  const unsigned pm[3]  = {0xFFFE0000u, 0xFFFFFE00u, 0xFFFFFFFEu};
  const int      shs[3] = {9, 1, 0};
  const int      wid[3] = {256, 256, 2};
  for (int pass = 0; pass < 3; ++pass){
    if (threadIdx.x < (unsigned)wid[pass]) h[threadIdx.x] = 0;
    __syncthreads();
    for (unsigned i = threadIdx.x; i < n; i += 256){
      unsigned k = cand[((size_t)b << 15) + i];
      if ((k & pm[pass]) == prefix)
        atomicAdd(&h[(k >> shs[pass]) & (unsigned)(wid[pass]-1)], 1u);
    }
    __syncthreads();
    if (threadIdx.x == 0){
      unsigned cum = 0; int bin = wid[pass]-1;
      for (; bin > 0; --bin){
        unsigned c = h[bin];
        if (cum + c >= krem) break;
        cum += c;
      }
      krem -= cum;
      prefix |= ((unsigned)bin) << shs[pass];
      sh2[0] = prefix; sh2[1] = krem;
    }
    __syncthreads();
    prefix = sh2[0]; krem = sh2[1];
    __syncthreads();
  }
  if (threadIdx.x == 0) tkey[b] = prefix;
}

__global__ __launch_bounds__(256)
void make_mask(const unsigned* __restrict__ Mkey, const unsigned* __restrict__ tkey,
               unsigned* __restrict__ mask){
  const int i = blockIdx.x * 256 + threadIdx.x;   // B*H = 65536
  const int b = i >> 12;
  mask[i] = (Mkey[i] >= tkey[b]) ? 1u : 0u;
}

extern "C" void kernel_launch(void* const* d_in, const int* in_sizes, int n_in,
                              void* d_out, int out_size, void* d_ws, size_t ws_size,
                              hipStream_t stream)
{
  (void)in_sizes; (void)n_in; (void)out_size; (void)ws_size;
  const float* X      = (const float*)d_in[0];
  const float* up_w   = (const float*)d_in[1];
  const float* up_b   = (const float*)d_in[2];
  const float* g1w    = (const float*)d_in[3];
  const float* g1b    = (const float*)d_in[4];
  const float* g2w    = (const float*)d_in[5];
  const float* g2b    = (const float*)d_in[6];
  const float* mod_w  = (const float*)d_in[7];
  const float* mod_b  = (const float*)d_in[8];
  const float* down_w = (const float*)d_in[9];
  const float* down_b = (const float*)d_in[10];
  float* out = (float*)d_out;

  // ws layout (peak ~235 MiB)
  char* ws = (char*)d_ws;
  _Float16* Xhi  = (_Float16*)(ws);
  _Float16* Xlo  = (_Float16*)(ws + (16ull<<20));
  _Float16* G1hi = (_Float16*)(ws + (32ull<<20));
  _Float16* G1lo = (_Float16*)(ws + (40ull<<20));
  _Float16* G2hi = (_Float16*)(ws + (48ull<<20));
  _Float16* G2lo = (_Float16*)(ws + (80ull<<20));
  _Float16* UPhi = (_Float16*)(ws + (112ull<<20));
  _Float16* MODhi= (_Float16*)(ws + (120ull<<20));
  _Float16* DWhi = (_Float16*)(ws + (128ull<<20));
  _Float16* Fhi  = (_Float16*)(ws + (136ull<<20));   // per half [4096][4096]
  _Float16* Flo  = (_Float16*)(ws + (168ull<<20));
  _Float16* Hbuf = (_Float16*)(ws + (136ull<<20));   // reuse after selection
  unsigned* keys = (unsigned*)(ws + (200ull<<20));   // per quarter [2048][4096]
  char* aux = ws + (232ull<<20);
  unsigned* Mkey  = (unsigned*)(aux);                 // 256 KB
  unsigned* maskb = (unsigned*)(aux + 262144);        // 256 KB
  unsigned* hist  = (unsigned*)(aux + 524288);        // 256 KB (16 batches x 4096)
  unsigned* cand  = (unsigned*)(aux + 786432);        // 2 MiB (16 x 32768)
  unsigned* b12   = (unsigned*)(aux + 786432 + 2097152);
  unsigned* krem  = (unsigned*)(aux + 786432 + 2097152 + 64);
  unsigned* ccnt  = (unsigned*)(aux + 786432 + 2097152 + 128);
  unsigned* tkey  = (unsigned*)(aux + 786432 + 2097152 + 192);

  // pack fp32 -> tiled fp16 images
  pack_img<true ><<<4096, 256, 0, stream>>>(X,      Xhi,  Xlo,  7, 32,  1048576);
  pack_img<true ><<<2048, 256, 0, stream>>>(g1w,    G1hi, G1lo, 7, 32,  524288);
  pack_img<true ><<<8192, 256, 0, stream>>>(g2w,    G2hi, G2lo, 9, 128, 2097152);
  pack_img<false><<<2048, 256, 0, stream>>>(up_w,   UPhi, nullptr, 7, 32,  524288);
  pack_img<false><<<2048, 256, 0, stream>>>(mod_w,  MODhi,nullptr, 7, 32,  524288);
  pack_img<false><<<2048, 256, 0, stream>>>(down_w, DWhi, nullptr, 9, 128, 524288);

  hipMemsetAsync(Mkey, 0, 262144, stream);
  hipMemsetAsync(hist, 0, 262144, stream);

  for (int half = 0; half < 2; ++half){
    // gate1 half: F = split(relu(X @ g1w^T + g1b))  [4096 x 4096], K=1024
    gemm_t<MODE_G1><<<dim3(32,32), 256, 0, stream>>>(
        Xhi, Xlo, G1hi, G1lo, g1b, nullptr, nullptr,
        Fhi, Flo, nullptr, nullptr, nullptr, nullptr,
        H_DIM, D_DIM, half*4096, half*4096, 0);
    for (int qd = 0; qd < 2; ++qd){
      const int b0 = half*8 + qd*4;
      // gate2 quarter: keys + Mkey + hist  [2048 x 4096], K=4096
      gemm_t<MODE_G2><<<dim3(32,16), 256, 0, stream>>>(
          Fhi, Flo, G2hi, G2lo, g2b, nullptr, nullptr,
          nullptr, nullptr, nullptr, keys, Mkey, hist,
          H_DIM, H_DIM, qd*2048, qd*2048, half*8);
      select12<<<4, 256, 0, stream>>>(hist, b12, krem, ccnt, b0);
      collect<<<dim3(256,4), 256, 0, stream>>>(keys, b12, cand, ccnt, b0);
      select_exact<<<4, 256, 0, stream>>>(cand, ccnt, b12, krem, tkey, b0);
    }
  }
  make_mask<<<256, 256, 0, stream>>>(Mkey, tkey, maskb);

  // up/mod row-select + silu -> Hbuf image  [8192 x 4096], K=1024
  gemm_t<MODE_UPMOD><<<dim3(32,64), 256, 0, stream>>>(
      Xhi, nullptr, UPhi, MODhi, up_b, mod_b, maskb,
      Hbuf, nullptr, nullptr, nullptr, nullptr, nullptr,
      H_DIM, D_DIM, 0, 0, 0);
  // down: out = Hbuf @ down_w^T + down_b  [8192 x 1024], K=4096
  gemm_t<MODE_DOWN><<<dim3(8,64), 256, 0, stream>>>(
      Hbuf, nullptr, DWhi, nullptr, down_b, nullptr, nullptr,
      nullptr, nullptr, out, nullptr, nullptr, nullptr,
      D_DIM, H_DIM, 0, 0, 0);
}